// Round 1
// baseline (570.055 us; speedup 1.0000x reference)
//
#include <hip/hip_runtime.h>

#define DEV __device__ __forceinline__

typedef short bf16x8 __attribute__((ext_vector_type(8)));
typedef float f32x4 __attribute__((ext_vector_type(4)));
typedef unsigned short u16;
typedef unsigned int u32;

typedef __attribute__((address_space(3))) void lds_void;
typedef __attribute__((address_space(1))) void gbl_void;

DEV void async_copy16(void* lds_dst, const void* g_src) {
    __builtin_amdgcn_global_load_lds((gbl_void*)g_src, (lds_void*)lds_dst, 16, 0, 0);
}

DEV u16 f2bf(float x) {
    u32 u = __float_as_uint(x);
    return (u16)((u + 0x7fffu + ((u >> 16) & 1u)) >> 16);
}
DEV u16 f2bf_fast(float x) {  // x >= 0, finite
    return (u16)((__float_as_uint(x) + 0x8000u) >> 16);
}
DEV float bf2f(u16 v) { return __uint_as_float(((u32)v) << 16); }

// ---------------------------------------------------------------------------
// fp32 -> bf16 conversion (vectorized by 4)
// ---------------------------------------------------------------------------
__global__ __launch_bounds__(256) void f2bf_kernel(const float* __restrict__ src,
                                                   u16* __restrict__ dst, int n4) {
    const int i = blockIdx.x * 256 + threadIdx.x;
    if (i < n4) {
        const float4 v = ((const float4*)src)[i];
        ushort4 o;
        o.x = f2bf(v.x); o.y = f2bf(v.y); o.z = f2bf(v.z); o.w = f2bf(v.w);
        ((ushort4*)dst)[i] = o;
    }
}

// ---------------------------------------------------------------------------
// Span scatter: RoPE row -> gate dot -> atomicAdd coef*tag_emb into out_pre
// ---------------------------------------------------------------------------
__global__ __launch_bounds__(256) void span_kernel(
    const float* __restrict__ we, const int* __restrict__ sb,
    const int* __restrict__ ss, const int* __restrict__ stg,
    const float* __restrict__ tag_emb, const float* __restrict__ gate_w,
    const float* __restrict__ gate_b, float* __restrict__ out_pre) {
    __shared__ float red[4];
    const int n = blockIdx.x >> 5;
    const int l = blockIdx.x & 31;
    const int t = threadIdx.x;
    const int b = sb[n];
    const int s = ss[n] + l;
    const int tag = stg[n];
    const long base = ((long)b * 1024 + s) * 1024;
    float dot = 0.f;
#pragma unroll
    for (int pp = 0; pp < 2; ++pp) {
        const int p = t + pp * 256;
        const float e1 = we[base + 2 * p];
        const float e2 = we[base + 2 * p + 1];
        const float inv = exp2f((float)p * (-13.287712379549449f / 512.0f));
        const float ang = (float)s * inv;
        const float sa = sinf(ang), ca = cosf(ang);
        const float r1 = e1 * ca - e2 * sa;
        const float r2 = e1 * sa + e2 * ca;
        dot += r1 * gate_w[2 * p] + r2 * gate_w[2 * p + 1];
    }
#pragma unroll
    for (int off = 32; off > 0; off >>= 1) dot += __shfl_xor(dot, off, 64);
    if ((t & 63) == 0) red[t >> 6] = dot;
    __syncthreads();
    const float z = red[0] + red[1] + red[2] + red[3] + gate_b[0];
    const float gate = 0.25f + 0.5f / (1.f + __expf(-z));
    const float coef = gate * 16.f;
    const float* te = tag_emb + (long)tag * 1024;
#pragma unroll
    for (int c = 0; c < 4; ++c) {
        const int d = t + c * 256;
        atomicAdd(&out_pre[base + d], coef * te[d]);
    }
}

// ---------------------------------------------------------------------------
// LayerNorm over D=1024, one block per row.
// ---------------------------------------------------------------------------
template <bool WRITE_F32, bool WRITE_BF, bool FINAL>
__global__ __launch_bounds__(256) void ln_kernel(
    const float* __restrict__ X, const float* __restrict__ g,
    const float* __restrict__ bta, float eps, float* __restrict__ Yf,
    u16* __restrict__ Ybf, const u16* __restrict__ addend) {
    __shared__ float red[8];
    const long row = blockIdx.x;
    const int t = threadIdx.x;
    const float4 x = ((const float4*)(X + row * 1024))[t];
    float s = x.x + x.y + x.z + x.w;
#pragma unroll
    for (int off = 32; off > 0; off >>= 1) s += __shfl_xor(s, off, 64);
    if ((t & 63) == 0) red[t >> 6] = s;
    __syncthreads();
    const float mean = (red[0] + red[1] + red[2] + red[3]) * (1.f / 1024.f);
    float4 dx;
    dx.x = x.x - mean; dx.y = x.y - mean; dx.z = x.z - mean; dx.w = x.w - mean;
    float ss = dx.x * dx.x + dx.y * dx.y + dx.z * dx.z + dx.w * dx.w;
#pragma unroll
    for (int off = 32; off > 0; off >>= 1) ss += __shfl_xor(ss, off, 64);
    if ((t & 63) == 0) red[4 + (t >> 6)] = ss;
    __syncthreads();
    const float var = (red[4] + red[5] + red[6] + red[7]) * (1.f / 1024.f);
    const float rstd = rsqrtf(var + eps);
    const float4 gv = ((const float4*)g)[t];
    const float4 bv = ((const float4*)bta)[t];
    float4 y;
    y.x = dx.x * rstd * gv.x + bv.x;
    y.y = dx.y * rstd * gv.y + bv.y;
    y.z = dx.z * rstd * gv.z + bv.z;
    y.w = dx.w * rstd * gv.w + bv.w;
    if (FINAL) {
        const ushort4 a = ((const ushort4*)(addend + row * 1024))[t];
        y.x += bf2f(a.x); y.y += bf2f(a.y); y.z += bf2f(a.z); y.w += bf2f(a.w);
    }
    if (WRITE_F32) ((float4*)(Yf + row * 1024))[t] = y;
    if (WRITE_BF) {
        ushort4 o;
        o.x = f2bf(y.x); o.y = f2bf(y.y); o.z = f2bf(y.z); o.w = f2bf(y.w);
        ((ushort4*)(Ybf + row * 1024))[t] = o;
    }
}

// ---------------------------------------------------------------------------
// NT GEMM v3 (kept for N=1024 shapes where the 256^2 grid would underfill):
// 16x16x32 MFMA, 4x4 acc/wave, 128x128 tile, BK=64, XOR slot-swizzled LDS.
// ---------------------------------------------------------------------------
template <bool OUT_BF16, bool RELU, bool HAS_RES>
__global__ __launch_bounds__(256, 2) void gemm_nt(
    const u16* __restrict__ A, const u16* __restrict__ B,
    const float* __restrict__ bias, const u16* __restrict__ res,
    void* __restrict__ Cout, int N, int K) {
    __shared__ u16 Al[8192];   // 128 rows x 64 k = 16 KB
    __shared__ u16 Bl[8192];
    const int tid = threadIdx.x;
    const int wave = tid >> 6;
    const int lane = tid & 63;
    const int quad = lane >> 4;
    const int lq = lane & 15;
    const int wm = wave >> 1;
    const int wn = wave & 1;
    const long rowBase = (long)blockIdx.x * 128;
    const long colBase = (long)blockIdx.y * 128;

    f32x4 acc[4][4];
    const f32x4 fzero = {0.f, 0.f, 0.f, 0.f};
#pragma unroll
    for (int i = 0; i < 4; ++i)
#pragma unroll
        for (int j = 0; j < 4; ++j) acc[i][j] = fzero;

    const int rX = tid >> 3;
    const int pX = (tid & 7) ^ (rX & 7);
    const u16* gA = A + (rowBase + rX) * (long)K + pX * 8;
    const u16* gB = B + (colBase + rX) * (long)K + pX * 8;
    u16* ldsA = Al + wave * 512;
    u16* ldsB = Bl + wave * 512;

    for (int kt = 0; kt < K; kt += 64) {
        __syncthreads();
#pragma unroll
        for (int c = 0; c < 4; ++c) {
            async_copy16(ldsA + c * 2048, gA + (long)c * 32 * K + kt);
            async_copy16(ldsB + c * 2048, gB + (long)c * 32 * K + kt);
        }
        __syncthreads();
#pragma unroll
        for (int ks = 0; ks < 2; ++ks) {
            bf16x8 af[4], bfr[4];
#pragma unroll
            for (int i = 0; i < 4; ++i) {
                const int r = wm * 64 + i * 16 + lq;
                af[i] = *(const bf16x8*)&Al[r * 64 + (((ks * 4 + quad) ^ (lq & 7)) * 8)];
            }
#pragma unroll
            for (int j = 0; j < 4; ++j) {
                const int r = wn * 64 + j * 16 + lq;
                bfr[j] = *(const bf16x8*)&Bl[r * 64 + (((ks * 4 + quad) ^ (lq & 7)) * 8)];
            }
#pragma unroll
            for (int i = 0; i < 4; ++i)
#pragma unroll
                for (int j = 0; j < 4; ++j)
                    acc[i][j] = __builtin_amdgcn_mfma_f32_16x16x32_bf16(
                        af[i], bfr[j], acc[i][j], 0, 0, 0);
        }
    }

    float biasv[4];
#pragma unroll
    for (int j = 0; j < 4; ++j) biasv[j] = bias[colBase + wn * 64 + j * 16 + lq];
#pragma unroll
    for (int i = 0; i < 4; ++i) {
        const long grow = rowBase + wm * 64 + i * 16 + quad * 4;
#pragma unroll
        for (int j = 0; j < 4; ++j) {
            const long gcol = colBase + wn * 64 + j * 16 + lq;
#pragma unroll
            for (int r = 0; r < 4; ++r) {
                float v = acc[i][j][r] + biasv[j];
                if (RELU) v = fmaxf(v, 0.f);
                if (HAS_RES) v += bf2f(res[(grow + r) * N + gcol]);
                if (OUT_BF16)
                    ((u16*)Cout)[(grow + r) * N + gcol] = f2bf(v);
                else
                    ((float*)Cout)[(grow + r) * N + gcol] = v;
            }
        }
    }
}

// ---------------------------------------------------------------------------
// NEW: 256x256 8-phase GEMM (T2+T3+T4+T5 from the verified m201 template).
// 512 threads = 8 waves (2 M x 4 N), per-wave output 128x64 (8x4 f32x4 acc).
// BK=64, LDS = 2 buf x (A 32KB + B 32KB) = 128 KiB. Same XOR slot swizzle as
// gemm_nt (pre-swizzled global source, linear LDS dest, XOR read -> 2-way
// bank aliasing = free).
//
// Per K-tile pair (buf0 = tile 2i, buf1 = tile 2i+1), 8 phases; each phase:
//   {ds-read frag subtile; stage 1 half-tile (2x global_load_lds);
//    s_barrier; lgkmcnt(0); setprio(1); 16 MFMA; setprio(0); s_barrier}
// Frag read schedule per K-tile: P1 A-top(8)+B-left(4) -> Q0; P2 B-right(4)
// -> Q1; P3 A-bot(8) -> Q2; P4 none -> Q3.  Region freedom: buf.B fully read
// after P2, buf.A after P3 -> stages trail reads by >=1 barrier (race-free).
// Stage order: P1..P3 finish tile 2i+1 (A1,B0,B1), P4..P7 tile 2i+2
// (A0,A1,B0,B1), P8 starts tile 2i+3 (A0).  s_waitcnt vmcnt(2) ONLY at end
// of P4/P8 (keeps 1 half-tile in flight across the barrier; never drains 0).
// ---------------------------------------------------------------------------
#define PH_SYNC()                                          \
    do {                                                   \
        __builtin_amdgcn_s_barrier();                      \
        asm volatile("s_waitcnt lgkmcnt(0)" ::: "memory"); \
        __builtin_amdgcn_sched_barrier(0);                 \
    } while (0)

template <bool RELU>
__global__ __launch_bounds__(512, 2) void gemm_nt8(
    const u16* __restrict__ A, const u16* __restrict__ B,
    const float* __restrict__ bias, u16* __restrict__ Cout, int N, int K) {
    __shared__ u16 Al[2][16384];  // [buf][row(256) * 64]
    __shared__ u16 Bl[2][16384];
    const int tid = threadIdx.x;
    const int wave = tid >> 6;
    const int lane = tid & 63;
    const int quad = lane >> 4;
    const int lq = lane & 15;
    const int lq7 = lq & 7;
    const int wm = wave >> 2;  // 0..1
    const int wn = wave & 3;   // 0..3
    const long rowBase = (long)blockIdx.x * 256;
    const long colBase = (long)blockIdx.y * 256;
    const int NT = K >> 6;  // K-tiles of 64

    // staging: slot s = c*512+tid (c=0,1) -> row s>>3 in half, LDS slot s&7,
    // source k-chunk (s&7)^(row&7).
    const int rs = tid >> 3;                 // 0..63
    const int js = (tid & 7) ^ (rs & 7);
    const u16* gA = A + (rowBase + rs) * (long)K + js * 8;
    const u16* gB = B + (colBase + rs) * (long)K + js * 8;

    f32x4 acc[8][4];
    const f32x4 fz = {0.f, 0.f, 0.f, 0.f};
#pragma unroll
    for (int i = 0; i < 8; ++i)
#pragma unroll
        for (int j = 0; j < 4; ++j) acc[i][j] = fz;

    auto stA = [&](int buf, int h, int t) {
        u16* d = &Al[buf][h * 8192 + wave * 512];  // wave-uniform base
        const u16* s = gA + (long)h * 128 * K + t * 64;
        async_copy16(d, s);
        async_copy16(d + 4096, s + (long)64 * K);
    };
    auto stB = [&](int buf, int h, int t) {
        u16* d = &Bl[buf][h * 8192 + wave * 512];
        const u16* s = gB + (long)h * 128 * K + t * 64;
        async_copy16(d, s);
        async_copy16(d + 4096, s + (long)64 * K);
    };
    auto ldA = [&](int buf, int i, int kh) {
        const int r = wm * 128 + i * 16 + lq;
        return *(const bf16x8*)&Al[buf][r * 64 + ((((kh << 2) | quad) ^ lq7) << 3)];
    };
    auto ldB = [&](int buf, int j, int kh) {
        const int r = wn * 64 + j * 16 + lq;
        return *(const bf16x8*)&Bl[buf][r * 64 + ((((kh << 2) | quad) ^ lq7) << 3)];
    };

    // prologue: tile0 complete + A0(tile1); leave A0(t1) in flight (vmcnt(2))
    stA(0, 0, 0); stA(0, 1, 0); stB(0, 0, 0); stB(0, 1, 0);
    stA(1, 0, 1);
    asm volatile("s_waitcnt vmcnt(2)" ::: "memory");
    __builtin_amdgcn_s_barrier();

    bf16x8 at[8], ab[8], bl[4], br[4];
    for (int it = 0; it < (NT >> 1); ++it) {
        const int t1 = 2 * it + 1;
        int t2 = 2 * it + 2; if (t2 >= NT) t2 -= NT;  // wrap: harmless re-stage
        int t3 = 2 * it + 3; if (t3 >= NT) t3 -= NT;

        // ================= K-tile 2it (buf 0) =================
        // P1: A-top + B-left -> Q0
#pragma unroll
        for (int i = 0; i < 4; ++i) { at[2 * i] = ldA(0, i, 0); at[2 * i + 1] = ldA(0, i, 1); }
#pragma unroll
        for (int j = 0; j < 2; ++j) { bl[2 * j] = ldB(0, j, 0); bl[2 * j + 1] = ldB(0, j, 1); }
        stA(1, 1, t1);
        PH_SYNC();
        __builtin_amdgcn_s_setprio(1);
#pragma unroll
        for (int i = 0; i < 4; ++i)
#pragma unroll
            for (int j = 0; j < 2; ++j)
#pragma unroll
                for (int kh = 0; kh < 2; ++kh)
                    acc[i][j] = __builtin_amdgcn_mfma_f32_16x16x32_bf16(
                        at[2 * i + kh], bl[2 * j + kh], acc[i][j], 0, 0, 0);
        __builtin_amdgcn_s_setprio(0);
        __builtin_amdgcn_s_barrier();
        // P2: B-right -> Q1
#pragma unroll
        for (int j = 0; j < 2; ++j) { br[2 * j] = ldB(0, j + 2, 0); br[2 * j + 1] = ldB(0, j + 2, 1); }
        stB(1, 0, t1);
        PH_SYNC();
        __builtin_amdgcn_s_setprio(1);
#pragma unroll
        for (int i = 0; i < 4; ++i)
#pragma unroll
            for (int j = 0; j < 2; ++j)
#pragma unroll
                for (int kh = 0; kh < 2; ++kh)
                    acc[i][j + 2] = __builtin_amdgcn_mfma_f32_16x16x32_bf16(
                        at[2 * i + kh], br[2 * j + kh], acc[i][j + 2], 0, 0, 0);
        __builtin_amdgcn_s_setprio(0);
        __builtin_amdgcn_s_barrier();
        // P3: A-bot -> Q2
#pragma unroll
        for (int i = 0; i < 4; ++i) { ab[2 * i] = ldA(0, i + 4, 0); ab[2 * i + 1] = ldA(0, i + 4, 1); }
        stB(1, 1, t1);
        PH_SYNC();
        __builtin_amdgcn_s_setprio(1);
#pragma unroll
        for (int i = 0; i < 4; ++i)
#pragma unroll
            for (int j = 0; j < 2; ++j)
#pragma unroll
                for (int kh = 0; kh < 2; ++kh)
                    acc[i + 4][j] = __builtin_amdgcn_mfma_f32_16x16x32_bf16(
                        ab[2 * i + kh], bl[2 * j + kh], acc[i + 4][j], 0, 0, 0);
        __builtin_amdgcn_s_setprio(0);
        __builtin_amdgcn_s_barrier();
        // P4: Q3 (no reads); counted vmcnt -> next half uses buf1
        stA(0, 0, t2);
        PH_SYNC();
        __builtin_amdgcn_s_setprio(1);
#pragma unroll
        for (int i = 0; i < 4; ++i)
#pragma unroll
            for (int j = 0; j < 2; ++j)
#pragma unroll
                for (int kh = 0; kh < 2; ++kh)
                    acc[i + 4][j + 2] = __builtin_amdgcn_mfma_f32_16x16x32_bf16(
                        ab[2 * i + kh], br[2 * j + kh], acc[i + 4][j + 2], 0, 0, 0);
        __builtin_amdgcn_s_setprio(0);
        asm volatile("s_waitcnt vmcnt(2)" ::: "memory");
        __builtin_amdgcn_s_barrier();

        // ================= K-tile 2it+1 (buf 1) =================
        // P5
#pragma unroll
        for (int i = 0; i < 4; ++i) { at[2 * i] = ldA(1, i, 0); at[2 * i + 1] = ldA(1, i, 1); }
#pragma unroll
        for (int j = 0; j < 2; ++j) { bl[2 * j] = ldB(1, j, 0); bl[2 * j + 1] = ldB(1, j, 1); }
        stA(0, 1, t2);
        PH_SYNC();
        __builtin_amdgcn_s_setprio(1);
#pragma unroll
        for (int i = 0; i < 4; ++i)
#pragma unroll
            for (int j = 0; j < 2; ++j)
#pragma unroll
                for (int kh = 0; kh < 2; ++kh)
                    acc[i][j] = __builtin_amdgcn_mfma_f32_16x16x32_bf16(
                        at[2 * i + kh], bl[2 * j + kh], acc[i][j], 0, 0, 0);
        __builtin_amdgcn_s_setprio(0);
        __builtin_amdgcn_s_barrier();
        // P6
#pragma unroll
        for (int j = 0; j < 2; ++j) { br[2 * j] = ldB(1, j + 2, 0); br[2 * j + 1] = ldB(1, j + 2, 1); }
        stB(0, 0, t2);
        PH_SYNC();
        __builtin_amdgcn_s_setprio(1);
#pragma unroll
        for (int i = 0; i < 4; ++i)
#pragma unroll
            for (int j = 0; j < 2; ++j)
#pragma unroll
                for (int kh = 0; kh < 2; ++kh)
                    acc[i][j + 2] = __builtin_amdgcn_mfma_f32_16x16x32_bf16(
                        at[2 * i + kh], br[2 * j + kh], acc[i][j + 2], 0, 0, 0);
        __builtin_amdgcn_s_setprio(0);
        __builtin_amdgcn_s_barrier();
        // P7
#pragma unroll
        for (int i = 0; i < 4; ++i) { ab[2 * i] = ldA(1, i + 4, 0); ab[2 * i + 1] = ldA(1, i + 4, 1); }
        stB(0, 1, t2);
        PH_SYNC();
        __builtin_amdgcn_s_setprio(1);
#pragma unroll
        for (int i = 0; i < 4; ++i)
#pragma unroll
            for (int j = 0; j < 2; ++j)
#pragma unroll
                for (int kh = 0; kh < 2; ++kh)
                    acc[i + 4][j] = __builtin_amdgcn_mfma_f32_16x16x32_bf16(
                        ab[2 * i + kh], bl[2 * j + kh], acc[i + 4][j], 0, 0, 0);
        __builtin_amdgcn_s_setprio(0);
        __builtin_amdgcn_s_barrier();
        // P8
        stA(1, 0, t3);
        PH_SYNC();
        __builtin_amdgcn_s_setprio(1);
#pragma unroll
        for (int i = 0; i < 4; ++i)
#pragma unroll
            for (int j = 0; j < 2; ++j)
#pragma unroll
                for (int kh = 0; kh < 2; ++kh)
                    acc[i + 4][j + 2] = __builtin_amdgcn_mfma_f32_16x16x32_bf16(
                        ab[2 * i + kh], br[2 * j + kh], acc[i + 4][j + 2], 0, 0, 0);
        __builtin_amdgcn_s_setprio(0);
        asm volatile("s_waitcnt vmcnt(2)" ::: "memory");
        __builtin_amdgcn_s_barrier();
    }

    asm volatile("s_waitcnt vmcnt(0)" ::: "memory");  // drain leftover stages
    float bv[4];
#pragma unroll
    for (int j = 0; j < 4; ++j) bv[j] = bias[colBase + wn * 64 + j * 16 + lq];
#pragma unroll
    for (int i = 0; i < 8; ++i) {
        const long grow = rowBase + wm * 128 + i * 16 + quad * 4;
#pragma unroll
        for (int j = 0; j < 4; ++j) {
            const long gcol = colBase + wn * 64 + j * 16 + lq;
#pragma unroll
            for (int r = 0; r < 4; ++r) {
                float v = acc[i][j][r] + bv[j];
                if (RELU) v = fmaxf(v, 0.f);
                Cout[(grow + r) * N + gcol] = f2bf(v);
            }
        }
    }
}

// ---------------------------------------------------------------------------
// V transpose: Vt[b,h,d,s] (bf16) <- QKV[(b*S+s)*3072 + 2048 + h*64 + d]
// ---------------------------------------------------------------------------
__global__ __launch_bounds__(256) void vtrans_kernel(const u16* __restrict__ QKV,
                                                     u16* __restrict__ Vt) {
    __shared__ u16 tile[64][72];
    const int bid = blockIdx.x;
    const int st = bid & 15;
    const int h = (bid >> 4) & 15;
    const int b = bid >> 8;
    const int t = threadIdx.x;
    const int sl = t >> 2;
    const int dc = (t & 3) * 16;
    const u16* src = QKV + ((long)(b * 1024 + st * 64 + sl)) * 3072 + 2048 + h * 64 + dc;
    *(uint4*)&tile[sl][dc] = *(const uint4*)src;
    *(uint4*)&tile[sl][dc + 8] = *(const uint4*)(src + 8);
    __syncthreads();
    const int dl = t >> 2;
    const int sc = (t & 3) * 16;
    union { u16 u[16]; uint4 q[2]; } tmp;
#pragma unroll
    for (int i = 0; i < 16; ++i) tmp.u[i] = tile[sc + i][dl];
    u16* dst = Vt + ((long)(b * 16 + h) * 64 + dl) * 1024 + st * 64 + sc;
    *(uint4*)dst = tmp.q[0];
    *(uint4*)(dst + 8) = tmp.q[1];
}

// ---------------------------------------------------------------------------
// Flash attention (unchanged).
// ---------------------------------------------------------------------------
__global__ __launch_bounds__(256, 4) void attn_kernel(
    const u16* __restrict__ QKV, const u16* __restrict__ Vt,
    const int* __restrict__ mask, u16* __restrict__ Out) {
    __shared__ u16 KL[4096];
    __shared__ u16 VL[4096];
    __shared__ u16 PL[4][16 * 72];
    const int tid = threadIdx.x;
    const int wid = tid >> 6;
    const int lane = tid & 63;
    const int quad = lane >> 4;
    const int lq = lane & 15;
    const int slot0 = quad ^ (lq & 7);
    const int slot1 = slot0 ^ 4;

    const int bid = blockIdx.x;
    const int qb = bid & 7;
    const int h = (bid >> 3) & 15;
    const int b = bid >> 7;
    const int qbase = qb * 128 + wid * 32;

    bf16x8 aq[2][2];
#pragma unroll
    for (int t = 0; t < 2; ++t) {
        const u16* qp = QKV + ((long)(b * 1024 + qbase + t * 16 + lq)) * 3072 +
                        h * 64 + quad * 8;
        aq[t][0] = *(const bf16x8*)qp;
        aq[t][1] = *(const bf16x8*)(qp + 32);
    }

    const int c0 = tid, c1 = 256 + tid;
    const int r0 = c0 >> 3, j0 = (c0 & 7) ^ (r0 & 7);
    const int r1 = c1 >> 3, j1 = (c1 & 7) ^ (r1 & 7);
    const u16* srcK0 = QKV + ((long)(b * 1024 + r0)) * 3072 + 1024 + h * 64 + j0 * 8;
    const u16* srcK1 = QKV + ((long)(b * 1024 + r1)) * 3072 + 1024 + h * 64 + j1 * 8;
    const u16* srcV0 = Vt + ((long)(b * 16 + h) * 64 + r0) * 1024 + j0 * 8;
    const u16* srcV1 = Vt + ((long)(b * 16 + h) * 64 + r1) * 1024 + j1 * 8;
    u16* ldsK0 = KL + wid * 512;
    u16* ldsK1 = KL + 2048 + wid * 512;
    u16* ldsV0 = VL + wid * 512;
    u16* ldsV1 = VL + 2048 + wid * 512;

    const f32x4 fzero = {0.f, 0.f, 0.f, 0.f};
    f32x4 acc[2][4];
#pragma unroll
    for (int t = 0; t < 2; ++t)
#pragma unroll
        for (int j = 0; j < 4; ++j) acc[t][j] = fzero;
    float lsum[2][4] = {{0.f, 0.f, 0.f, 0.f}, {0.f, 0.f, 0.f, 0.f}};
    u16* myP = PL[wid];
    const int* mrow = mask + b * 1024;

    for (int kt = 0; kt < 1024; kt += 64) {
        __syncthreads();
        async_copy16(ldsK0, srcK0 + (long)kt * 3072);
        async_copy16(ldsK1, srcK1 + (long)kt * 3072);
        async_copy16(ldsV0, srcV0 + kt);
        async_copy16(ldsV1, srcV1 + kt);
        __syncthreads();

        bf16x8 kf0[4], kf1[4];
#pragma unroll
        for (int ct = 0; ct < 4; ++ct) {
            const int rowb = (ct * 16 + lq) * 64;
            kf0[ct] = *(const bf16x8*)&KL[rowb + slot0 * 8];
            kf1[ct] = *(const bf16x8*)&KL[rowb + slot1 * 8];
        }
        float mw[4];
#pragma unroll
        for (int ct = 0; ct < 4; ++ct) mw[ct] = mrow[kt + ct * 16 + lq] ? 1.f : 0.f;

#pragma unroll
        for (int t = 0; t < 2; ++t) {
            f32x4 s[4];
#pragma unroll
            for (int ct = 0; ct < 4; ++ct) {
                s[ct] = __builtin_amdgcn_mfma_f32_16x16x32_bf16(aq[t][0], kf0[ct],
                                                                fzero, 0, 0, 0);
                s[ct] = __builtin_amdgcn_mfma_f32_16x16x32_bf16(aq[t][1], kf1[ct],
                                                                s[ct], 0, 0, 0);
            }
            asm volatile("s_waitcnt lgkmcnt(0)" ::: "memory");
#pragma unroll
            for (int ct = 0; ct < 4; ++ct)
#pragma unroll
                for (int r = 0; r < 4; ++r) {
                    const float p = mw[ct] * __expf(s[ct][r] * 0.125f);
                    lsum[t][r] += p;
                    myP[(quad * 4 + r) * 72 + ct * 16 + lq] = f2bf_fast(p);
                }
            asm volatile("s_waitcnt lgkmcnt(0)" ::: "memory");
            const bf16x8 pf0 = *(const bf16x8*)&myP[lq * 72 + quad * 8];
            const bf16x8 pf1 = *(const bf16x8*)&myP[lq * 72 + 32 + quad * 8];
#pragma unroll
            for (int j = 0; j < 4; ++j) {
                const int rowb = (j * 16 + lq) * 64;
                const bf16x8 vf0 = *(const bf16x8*)&VL[rowb + slot0 * 8];
                const bf16x8 vf1 = *(const bf16x8*)&VL[rowb + slot1 * 8];
                acc[t][j] = __builtin_amdgcn_mfma_f32_16x16x32_bf16(pf0, vf0,
                                                                    acc[t][j], 0, 0, 0);
                acc[t][j] = __builtin_amdgcn_mfma_f32_16x16x32_bf16(pf1, vf1,
                                                                    acc[t][j], 0, 0, 0);
            }
        }
    }

#pragma unroll
    for (int t = 0; t < 2; ++t) {
        float inv[4];
#pragma unroll
        for (int r = 0; r < 4; ++r) {
            float l = lsum[t][r];
#pragma unroll
            for (int off = 1; off < 16; off <<= 1) l += __shfl_xor(l, off, 16);
            inv[r] = 1.f / l;
        }
        const long orow = (long)b * 1024 + qbase + t * 16 + quad * 4;
#pragma unroll
        for (int j = 0; j < 4; ++j)
#pragma unroll
            for (int r = 0; r < 4; ++r)
                Out[(orow + r) * 1024 + h * 64 + j * 16 + lq] =
                    f2bf_fast(acc[t][j][r] * inv[r]);
    }
}

// ---------------------------------------------------------------------------
extern "C" void kernel_launch(void* const* d_in, const int* in_sizes, int n_in,
                              void* d_out, int out_size, void* d_ws, size_t ws_size,
                              hipStream_t stream) {
    const float* we        = (const float*)d_in[0];
    const int*   amask     = (const int*)d_in[1];
    const int*   span_b    = (const int*)d_in[2];
    const int*   span_s    = (const int*)d_in[3];
    const int*   span_t    = (const int*)d_in[4];
    const float* tag_emb   = (const float*)d_in[5];
    const float* gate_w    = (const float*)d_in[6];
    const float* gate_b    = (const float*)d_in[7];
    const float* attn_ln_g = (const float*)d_in[8];
    const float* attn_ln_b = (const float*)d_in[9];
    const float* in_proj_w = (const float*)d_in[10];
    const float* in_proj_b = (const float*)d_in[11];
    const float* out_proj_w= (const float*)d_in[12];
    const float* out_proj_b= (const float*)d_in[13];
    const float* enc1_g    = (const float*)d_in[14];
    const float* enc1_b    = (const float*)d_in[15];
    const float* lin1_w    = (const float*)d_in[16];
    const float* lin1_b    = (const float*)d_in[17];
    const float* lin2_w    = (const float*)d_in[18];
    const float* lin2_b    = (const float*)d_in[19];
    const float* enc2_g    = (const float*)d_in[20];
    const float* enc2_b    = (const float*)d_in[21];
    float* out = (float*)d_out;  // also fp32 scratch (out_pre/h1/h2)

    char* ws = (char*)d_ws;
    size_t off = 0;
    auto alloc = [&](size_t bytes) {
        void* p = ws + off;
        off += (bytes + 255) & ~(size_t)255;
        return p;
    };
    const size_t MT = 8192;
    u16* oe_bf   = (u16*)alloc(MT * 1024 * 2);
    u16* ax_bf   = (u16*)alloc(MT * 1024 * 2);
    char* region = (char*)alloc((size_t)67108864);             // qkv+vt | ff1
    u16* qkv_bf  = (u16*)region;
    u16* vt_bf   = (u16*)(region + (size_t)MT * 3072 * 2);
    u16* ff1_bf  = (u16*)region;
    u16* wb_inproj  = (u16*)alloc((size_t)3072 * 1024 * 2);
    u16* wb_outproj = (u16*)alloc((size_t)1024 * 1024 * 2);
    u16* wb_lin1    = (u16*)alloc((size_t)4096 * 1024 * 2);
    u16* wb_lin2    = (u16*)alloc((size_t)1024 * 4096 * 2);

    hipMemcpyAsync(out, we, MT * 1024 * 4, hipMemcpyDeviceToDevice, stream);
    f2bf_kernel<<<3072, 256, 0, stream>>>(in_proj_w, wb_inproj, 3072 * 1024 / 4);
    f2bf_kernel<<<1024, 256, 0, stream>>>(out_proj_w, wb_outproj, 1024 * 1024 / 4);
    f2bf_kernel<<<4096, 256, 0, stream>>>(lin1_w, wb_lin1, 4096 * 1024 / 4);
    f2bf_kernel<<<4096, 256, 0, stream>>>(lin2_w, wb_lin2, 1024 * 4096 / 4);
    span_kernel<<<16384, 256, 0, stream>>>(we, span_b, span_s, span_t, tag_emb,
                                           gate_w, gate_b, out);
    ln_kernel<false, true, false><<<8192, 256, 0, stream>>>(
        out, attn_ln_g, attn_ln_b, 1e-12f, nullptr, oe_bf, nullptr);
    dim3 g1(32, 12);
    gemm_nt8<false><<<g1, 512, 0, stream>>>(oe_bf, wb_inproj, in_proj_b,
                                            qkv_bf, 3072, 1024);
    vtrans_kernel<<<2048, 256, 0, stream>>>(qkv_bf, vt_bf);
    attn_kernel<<<1024, 256, 0, stream>>>(qkv_bf, vt_bf, amask, ax_bf);
    dim3 g2(64, 8);
    gemm_nt<false, false, true><<<g2, 256, 0, stream>>>(ax_bf, wb_outproj, out_proj_b,
                                                        oe_bf, out, 1024, 1024);
    ln_kernel<false, true, false><<<8192, 256, 0, stream>>>(
        out, enc1_g, enc1_b, 1e-5f, nullptr, ax_bf, nullptr);
    dim3 g3(32, 16);
    gemm_nt8<true><<<g3, 512, 0, stream>>>(ax_bf, wb_lin1, lin1_b,
                                           ff1_bf, 4096, 1024);
    gemm_nt<false, false, true><<<g2, 256, 0, stream>>>(ff1_bf, wb_lin2, lin2_b,
                                                        ax_bf, out, 1024, 4096);
    ln_kernel<true, false, true><<<8192, 256, 0, stream>>>(
        out, enc2_g, enc2_b, 1e-5f, out, nullptr, oe_bf);
}

// Round 2
// 557.892 us; speedup vs baseline: 1.0218x; 1.0218x over previous
//
#include <hip/hip_runtime.h>

#define DEV __device__ __forceinline__

typedef short bf16x8 __attribute__((ext_vector_type(8)));
typedef float f32x4 __attribute__((ext_vector_type(4)));
typedef unsigned short u16;
typedef unsigned int u32;

typedef __attribute__((address_space(3))) void lds_void;
typedef __attribute__((address_space(1))) void gbl_void;

DEV void async_copy16(void* lds_dst, const void* g_src) {
    __builtin_amdgcn_global_load_lds((gbl_void*)g_src, (lds_void*)lds_dst, 16, 0, 0);
}

DEV u16 f2bf(float x) {
    u32 u = __float_as_uint(x);
    return (u16)((u + 0x7fffu + ((u >> 16) & 1u)) >> 16);
}
DEV u16 f2bf_fast(float x) {  // x >= 0, finite
    return (u16)((__float_as_uint(x) + 0x8000u) >> 16);
}
DEV float bf2f(u16 v) { return __uint_as_float(((u32)v) << 16); }

// ---------------------------------------------------------------------------
// fp32 -> bf16 conversion (vectorized by 4)
// ---------------------------------------------------------------------------
__global__ __launch_bounds__(256) void f2bf_kernel(const float* __restrict__ src,
                                                   u16* __restrict__ dst, int n4) {
    const int i = blockIdx.x * 256 + threadIdx.x;
    if (i < n4) {
        const float4 v = ((const float4*)src)[i];
        ushort4 o;
        o.x = f2bf(v.x); o.y = f2bf(v.y); o.z = f2bf(v.z); o.w = f2bf(v.w);
        ((ushort4*)dst)[i] = o;
    }
}

// ---------------------------------------------------------------------------
// Span scatter: RoPE row -> gate dot -> atomicAdd coef*tag_emb into out_pre
// ---------------------------------------------------------------------------
__global__ __launch_bounds__(256) void span_kernel(
    const float* __restrict__ we, const int* __restrict__ sb,
    const int* __restrict__ ss, const int* __restrict__ stg,
    const float* __restrict__ tag_emb, const float* __restrict__ gate_w,
    const float* __restrict__ gate_b, float* __restrict__ out_pre) {
    __shared__ float red[4];
    const int n = blockIdx.x >> 5;
    const int l = blockIdx.x & 31;
    const int t = threadIdx.x;
    const int b = sb[n];
    const int s = ss[n] + l;
    const int tag = stg[n];
    const long base = ((long)b * 1024 + s) * 1024;
    float dot = 0.f;
#pragma unroll
    for (int pp = 0; pp < 2; ++pp) {
        const int p = t + pp * 256;
        const float e1 = we[base + 2 * p];
        const float e2 = we[base + 2 * p + 1];
        const float inv = exp2f((float)p * (-13.287712379549449f / 512.0f));
        const float ang = (float)s * inv;
        const float sa = sinf(ang), ca = cosf(ang);
        const float r1 = e1 * ca - e2 * sa;
        const float r2 = e1 * sa + e2 * ca;
        dot += r1 * gate_w[2 * p] + r2 * gate_w[2 * p + 1];
    }
#pragma unroll
    for (int off = 32; off > 0; off >>= 1) dot += __shfl_xor(dot, off, 64);
    if ((t & 63) == 0) red[t >> 6] = dot;
    __syncthreads();
    const float z = red[0] + red[1] + red[2] + red[3] + gate_b[0];
    const float gate = 0.25f + 0.5f / (1.f + __expf(-z));
    const float coef = gate * 16.f;
    const float* te = tag_emb + (long)tag * 1024;
#pragma unroll
    for (int c = 0; c < 4; ++c) {
        const int d = t + c * 256;
        atomicAdd(&out_pre[base + d], coef * te[d]);
    }
}

// ---------------------------------------------------------------------------
// LayerNorm over D=1024, one block per row.
// ---------------------------------------------------------------------------
template <bool WRITE_F32, bool WRITE_BF, bool FINAL>
__global__ __launch_bounds__(256) void ln_kernel(
    const float* __restrict__ X, const float* __restrict__ g,
    const float* __restrict__ bta, float eps, float* __restrict__ Yf,
    u16* __restrict__ Ybf, const u16* __restrict__ addend) {
    __shared__ float red[8];
    const long row = blockIdx.x;
    const int t = threadIdx.x;
    const float4 x = ((const float4*)(X + row * 1024))[t];
    float s = x.x + x.y + x.z + x.w;
#pragma unroll
    for (int off = 32; off > 0; off >>= 1) s += __shfl_xor(s, off, 64);
    if ((t & 63) == 0) red[t >> 6] = s;
    __syncthreads();
    const float mean = (red[0] + red[1] + red[2] + red[3]) * (1.f / 1024.f);
    float4 dx;
    dx.x = x.x - mean; dx.y = x.y - mean; dx.z = x.z - mean; dx.w = x.w - mean;
    float ss = dx.x * dx.x + dx.y * dx.y + dx.z * dx.z + dx.w * dx.w;
#pragma unroll
    for (int off = 32; off > 0; off >>= 1) ss += __shfl_xor(ss, off, 64);
    if ((t & 63) == 0) red[4 + (t >> 6)] = ss;
    __syncthreads();
    const float var = (red[4] + red[5] + red[6] + red[7]) * (1.f / 1024.f);
    const float rstd = rsqrtf(var + eps);
    const float4 gv = ((const float4*)g)[t];
    const float4 bv = ((const float4*)bta)[t];
    float4 y;
    y.x = dx.x * rstd * gv.x + bv.x;
    y.y = dx.y * rstd * gv.y + bv.y;
    y.z = dx.z * rstd * gv.z + bv.z;
    y.w = dx.w * rstd * gv.w + bv.w;
    if (FINAL) {
        const ushort4 a = ((const ushort4*)(addend + row * 1024))[t];
        y.x += bf2f(a.x); y.y += bf2f(a.y); y.z += bf2f(a.z); y.w += bf2f(a.w);
    }
    if (WRITE_F32) ((float4*)(Yf + row * 1024))[t] = y;
    if (WRITE_BF) {
        ushort4 o;
        o.x = f2bf(y.x); o.y = f2bf(y.y); o.z = f2bf(y.z); o.w = f2bf(y.w);
        ((ushort4*)(Ybf + row * 1024))[t] = o;
    }
}

// ---------------------------------------------------------------------------
// 256x128-tile 8-phase GEMM (all four GEMM shapes -> exact multiples of 256
// workgroups: lin2/outproj 32x8=256, QKV 32x24=768, lin1 32x32=1024).
//
// 512 threads = 8 waves (4 M x 2 N), per-wave output 64x64 (acc[4][4]).
// Triple-buffered LDS: 3 x (A 256x64 + B 128x64) bf16 = 3 x 48KB = 144KB.
// 2 phases per K-tile, 16 MFMA per phase per wave.
// Stage granularity: 1 unit = 512 threads x 16B = 8KB = 64 rows; 6 units per
// K-tile (A:4, B:2), 3 issued per phase, targeting buf[(t+2)%3] (last read at
// tile t-1, all reads completed behind barrier+lgkmcnt(0)+barrier => safe).
// Counted vmcnt(6) once per K-tile (end of P2, before closing barrier):
// waits tile t+1's 6 units (issued during t-1, ~2 tiles = >1200cy ago, covers
// HBM latency), leaves tile t+2's 6 in flight. Never drains to 0 in the loop.
// XOR slot swizzle (as proven in gemm_nt): LDS slot s of row r holds source
// k-chunk s^(r&7); reads use slot g^(r&7) -> 2 lanes/bank group = free.
// ---------------------------------------------------------------------------
#define PH_SYNC()                                          \
    do {                                                   \
        __builtin_amdgcn_s_barrier();                      \
        asm volatile("s_waitcnt lgkmcnt(0)" ::: "memory"); \
        __builtin_amdgcn_sched_barrier(0);                 \
    } while (0)

template <bool OUT_BF16, bool RELU, bool HAS_RES>
__global__ __launch_bounds__(512, 2) void gemm_nt8b(
    const u16* __restrict__ A, const u16* __restrict__ B,
    const float* __restrict__ bias, const u16* __restrict__ res,
    void* __restrict__ Cout, int N, int K) {
    __shared__ u16 LT[3][24576];  // per buf: A = [0,16384) rows 256x64, B = [16384,24576) rows 128x64
    const int tid = threadIdx.x;
    const int wave = tid >> 6;
    const int lane = tid & 63;
    const int quad = lane >> 4;
    const int lq = lane & 15;
    const int lq7 = lq & 7;
    const int wm = wave >> 1;  // 0..3 : 64-row band
    const int wn = wave & 1;   // 0..1 : 64-col band
    const long rowBase = (long)blockIdx.x * 256;
    const long colBase = (long)blockIdx.y * 128;
    const int NT = K >> 6;

    // staging geometry: rs = row within 64-row unit, js = pre-swizzled k-chunk
    const int rs = tid >> 3;  // 0..63
    const int js = (tid & 7) ^ (rs & 7);
    const u16* gA = A + (rowBase + rs) * (long)K + js * 8;
    const u16* gB = B + (colBase + rs) * (long)K + js * 8;
    const long s64K = (long)64 * K;

    f32x4 acc[4][4];
    const f32x4 fz = {0.f, 0.f, 0.f, 0.f};
#pragma unroll
    for (int i = 0; i < 4; ++i)
#pragma unroll
        for (int j = 0; j < 4; ++j) acc[i][j] = fz;

    auto stage = [&](int so, int u, int t) {
        u16* d = &LT[0][0] + so + u * 4096 + wave * 512;  // wave-uniform base
        const u16* s = (u < 4 ? gA + u * s64K : gB + (u - 4) * s64K) + (long)t * 64;
        async_copy16(d, s);
    };
    auto ldA = [&](int bo, int i, int kh) {
        const int r = wm * 64 + i * 16 + lq;
        return *(const bf16x8*)(&LT[0][0] + bo + r * 64 +
                                ((((kh << 2) | quad) ^ lq7) << 3));
    };
    auto ldB = [&](int bo, int j, int kh) {
        const int r = wn * 64 + j * 16 + lq;
        return *(const bf16x8*)(&LT[0][0] + bo + 16384 + r * 64 +
                                ((((kh << 2) | quad) ^ lq7) << 3));
    };

    // prologue: stage tiles 0 and 1 fully (12 units); wait all but newest 6.
#pragma unroll
    for (int u = 0; u < 6; ++u) stage(0, u, 0);
#pragma unroll
    for (int u = 0; u < 6; ++u) stage(24576, u, 1);
    asm volatile("s_waitcnt vmcnt(6)" ::: "memory");
    __builtin_amdgcn_s_barrier();

    int bo = 0;          // buffer being computed (tile t)
    int so = 2 * 24576;  // buffer being staged (tile t+2)
    for (int t = 0; t < NT; ++t) {
        int tp2 = t + 2;
        if (tp2 >= NT) tp2 -= NT;  // wrapped source; dest buffer unused again
        bf16x8 a8[8], bb[8];
        // ---- P1: read A (all) + B cols 0..31; MFMA quadrants j=0,1 ----
#pragma unroll
        for (int i = 0; i < 4; ++i) { a8[2 * i] = ldA(bo, i, 0); a8[2 * i + 1] = ldA(bo, i, 1); }
#pragma unroll
        for (int j = 0; j < 2; ++j) { bb[2 * j] = ldB(bo, j, 0); bb[2 * j + 1] = ldB(bo, j, 1); }
        stage(so, 0, tp2); stage(so, 1, tp2); stage(so, 2, tp2);
        PH_SYNC();
        __builtin_amdgcn_s_setprio(1);
#pragma unroll
        for (int i = 0; i < 4; ++i)
#pragma unroll
            for (int j = 0; j < 2; ++j)
#pragma unroll
                for (int kh = 0; kh < 2; ++kh)
                    acc[i][j] = __builtin_amdgcn_mfma_f32_16x16x32_bf16(
                        a8[2 * i + kh], bb[2 * j + kh], acc[i][j], 0, 0, 0);
        __builtin_amdgcn_s_setprio(0);
        __builtin_amdgcn_s_barrier();
        // ---- P2: read B cols 32..63; MFMA quadrants j=2,3 ----
#pragma unroll
        for (int j = 0; j < 2; ++j) { bb[4 + 2 * j] = ldB(bo, j + 2, 0); bb[4 + 2 * j + 1] = ldB(bo, j + 2, 1); }
        stage(so, 3, tp2); stage(so, 4, tp2); stage(so, 5, tp2);
        PH_SYNC();
        __builtin_amdgcn_s_setprio(1);
#pragma unroll
        for (int i = 0; i < 4; ++i)
#pragma unroll
            for (int j = 0; j < 2; ++j)
#pragma unroll
                for (int kh = 0; kh < 2; ++kh)
                    acc[i][j + 2] = __builtin_amdgcn_mfma_f32_16x16x32_bf16(
                        a8[2 * i + kh], bb[4 + 2 * j + kh], acc[i][j + 2], 0, 0, 0);
        __builtin_amdgcn_s_setprio(0);
        asm volatile("s_waitcnt vmcnt(6)" ::: "memory");
        __builtin_amdgcn_s_barrier();
        bo += 24576; if (bo == 3 * 24576) bo = 0;
        so += 24576; if (so == 3 * 24576) so = 0;
    }

    asm volatile("s_waitcnt vmcnt(0)" ::: "memory");  // drain leftover stages
    float bv[4];
#pragma unroll
    for (int j = 0; j < 4; ++j) bv[j] = bias[colBase + wn * 64 + j * 16 + lq];
#pragma unroll
    for (int i = 0; i < 4; ++i) {
        const long grow = rowBase + wm * 64 + i * 16 + quad * 4;
#pragma unroll
        for (int j = 0; j < 4; ++j) {
            const long gcol = colBase + wn * 64 + j * 16 + lq;
#pragma unroll
            for (int r = 0; r < 4; ++r) {
                float v = acc[i][j][r] + bv[j];
                if (RELU) v = fmaxf(v, 0.f);
                if (HAS_RES) v += bf2f(res[(grow + r) * N + gcol]);
                if (OUT_BF16)
                    ((u16*)Cout)[(grow + r) * N + gcol] = f2bf(v);
                else
                    ((float*)Cout)[(grow + r) * N + gcol] = v;
            }
        }
    }
}

// ---------------------------------------------------------------------------
// V transpose: Vt[b,h,d,s] (bf16) <- QKV[(b*S+s)*3072 + 2048 + h*64 + d]
// ---------------------------------------------------------------------------
__global__ __launch_bounds__(256) void vtrans_kernel(const u16* __restrict__ QKV,
                                                     u16* __restrict__ Vt) {
    __shared__ u16 tile[64][72];
    const int bid = blockIdx.x;
    const int st = bid & 15;
    const int h = (bid >> 4) & 15;
    const int b = bid >> 8;
    const int t = threadIdx.x;
    const int sl = t >> 2;
    const int dc = (t & 3) * 16;
    const u16* src = QKV + ((long)(b * 1024 + st * 64 + sl)) * 3072 + 2048 + h * 64 + dc;
    *(uint4*)&tile[sl][dc] = *(const uint4*)src;
    *(uint4*)&tile[sl][dc + 8] = *(const uint4*)(src + 8);
    __syncthreads();
    const int dl = t >> 2;
    const int sc = (t & 3) * 16;
    union { u16 u[16]; uint4 q[2]; } tmp;
#pragma unroll
    for (int i = 0; i < 16; ++i) tmp.u[i] = tile[sc + i][dl];
    u16* dst = Vt + ((long)(b * 16 + h) * 64 + dl) * 1024 + st * 64 + sc;
    *(uint4*)dst = tmp.q[0];
    *(uint4*)(dst + 8) = tmp.q[1];
}

// ---------------------------------------------------------------------------
// Flash attention (unchanged).
// ---------------------------------------------------------------------------
__global__ __launch_bounds__(256, 4) void attn_kernel(
    const u16* __restrict__ QKV, const u16* __restrict__ Vt,
    const int* __restrict__ mask, u16* __restrict__ Out) {
    __shared__ u16 KL[4096];
    __shared__ u16 VL[4096];
    __shared__ u16 PL[4][16 * 72];
    const int tid = threadIdx.x;
    const int wid = tid >> 6;
    const int lane = tid & 63;
    const int quad = lane >> 4;
    const int lq = lane & 15;
    const int slot0 = quad ^ (lq & 7);
    const int slot1 = slot0 ^ 4;

    const int bid = blockIdx.x;
    const int qb = bid & 7;
    const int h = (bid >> 3) & 15;
    const int b = bid >> 7;
    const int qbase = qb * 128 + wid * 32;

    bf16x8 aq[2][2];
#pragma unroll
    for (int t = 0; t < 2; ++t) {
        const u16* qp = QKV + ((long)(b * 1024 + qbase + t * 16 + lq)) * 3072 +
                        h * 64 + quad * 8;
        aq[t][0] = *(const bf16x8*)qp;
        aq[t][1] = *(const bf16x8*)(qp + 32);
    }

    const int c0 = tid, c1 = 256 + tid;
    const int r0 = c0 >> 3, j0 = (c0 & 7) ^ (r0 & 7);
    const int r1 = c1 >> 3, j1 = (c1 & 7) ^ (r1 & 7);
    const u16* srcK0 = QKV + ((long)(b * 1024 + r0)) * 3072 + 1024 + h * 64 + j0 * 8;
    const u16* srcK1 = QKV + ((long)(b * 1024 + r1)) * 3072 + 1024 + h * 64 + j1 * 8;
    const u16* srcV0 = Vt + ((long)(b * 16 + h) * 64 + r0) * 1024 + j0 * 8;
    const u16* srcV1 = Vt + ((long)(b * 16 + h) * 64 + r1) * 1024 + j1 * 8;
    u16* ldsK0 = KL + wid * 512;
    u16* ldsK1 = KL + 2048 + wid * 512;
    u16* ldsV0 = VL + wid * 512;
    u16* ldsV1 = VL + 2048 + wid * 512;

    const f32x4 fzero = {0.f, 0.f, 0.f, 0.f};
    f32x4 acc[2][4];
#pragma unroll
    for (int t = 0; t < 2; ++t)
#pragma unroll
        for (int j = 0; j < 4; ++j) acc[t][j] = fzero;
    float lsum[2][4] = {{0.f, 0.f, 0.f, 0.f}, {0.f, 0.f, 0.f, 0.f}};
    u16* myP = PL[wid];
    const int* mrow = mask + b * 1024;

    for (int kt = 0; kt < 1024; kt += 64) {
        __syncthreads();
        async_copy16(ldsK0, srcK0 + (long)kt * 3072);
        async_copy16(ldsK1, srcK1 + (long)kt * 3072);
        async_copy16(ldsV0, srcV0 + kt);
        async_copy16(ldsV1, srcV1 + kt);
        __syncthreads();

        bf16x8 kf0[4], kf1[4];
#pragma unroll
        for (int ct = 0; ct < 4; ++ct) {
            const int rowb = (ct * 16 + lq) * 64;
            kf0[ct] = *(const bf16x8*)&KL[rowb + slot0 * 8];
            kf1[ct] = *(const bf16x8*)&KL[rowb + slot1 * 8];
        }
        float mw[4];
#pragma unroll
        for (int ct = 0; ct < 4; ++ct) mw[ct] = mrow[kt + ct * 16 + lq] ? 1.f : 0.f;

#pragma unroll
        for (int t = 0; t < 2; ++t) {
            f32x4 s[4];
#pragma unroll
            for (int ct = 0; ct < 4; ++ct) {
                s[ct] = __builtin_amdgcn_mfma_f32_16x16x32_bf16(aq[t][0], kf0[ct],
                                                                fzero, 0, 0, 0);
                s[ct] = __builtin_amdgcn_mfma_f32_16x16x32_bf16(aq[t][1], kf1[ct],
                                                                s[ct], 0, 0, 0);
            }
            asm volatile("s_waitcnt lgkmcnt(0)" ::: "memory");
#pragma unroll
            for (int ct = 0; ct < 4; ++ct)
#pragma unroll
                for (int r = 0; r < 4; ++r) {
                    const float p = mw[ct] * __expf(s[ct][r] * 0.125f);
                    lsum[t][r] += p;
                    myP[(quad * 4 + r) * 72 + ct * 16 + lq] = f2bf_fast(p);
                }
            asm volatile("s_waitcnt lgkmcnt(0)" ::: "memory");
            const bf16x8 pf0 = *(const bf16x8*)&myP[lq * 72 + quad * 8];
            const bf16x8 pf1 = *(const bf16x8*)&myP[lq * 72 + 32 + quad * 8];
#pragma unroll
            for (int j = 0; j < 4; ++j) {
                const int rowb = (j * 16 + lq) * 64;
                const bf16x8 vf0 = *(const bf16x8*)&VL[rowb + slot0 * 8];
                const bf16x8 vf1 = *(const bf16x8*)&VL[rowb + slot1 * 8];
                acc[t][j] = __builtin_amdgcn_mfma_f32_16x16x32_bf16(pf0, vf0,
                                                                    acc[t][j], 0, 0, 0);
                acc[t][j] = __builtin_amdgcn_mfma_f32_16x16x32_bf16(pf1, vf1,
                                                                    acc[t][j], 0, 0, 0);
            }
        }
    }

#pragma unroll
    for (int t = 0; t < 2; ++t) {
        float inv[4];
#pragma unroll
        for (int r = 0; r < 4; ++r) {
            float l = lsum[t][r];
#pragma unroll
            for (int off = 1; off < 16; off <<= 1) l += __shfl_xor(l, off, 16);
            inv[r] = 1.f / l;
        }
        const long orow = (long)b * 1024 + qbase + t * 16 + quad * 4;
#pragma unroll
        for (int j = 0; j < 4; ++j)
#pragma unroll
            for (int r = 0; r < 4; ++r)
                Out[(orow + r) * 1024 + h * 64 + j * 16 + lq] =
                    f2bf_fast(acc[t][j][r] * inv[r]);
    }
}

// ---------------------------------------------------------------------------
extern "C" void kernel_launch(void* const* d_in, const int* in_sizes, int n_in,
                              void* d_out, int out_size, void* d_ws, size_t ws_size,
                              hipStream_t stream) {
    const float* we        = (const float*)d_in[0];
    const int*   amask     = (const int*)d_in[1];
    const int*   span_b    = (const int*)d_in[2];
    const int*   span_s    = (const int*)d_in[3];
    const int*   span_t    = (const int*)d_in[4];
    const float* tag_emb   = (const float*)d_in[5];
    const float* gate_w    = (const float*)d_in[6];
    const float* gate_b    = (const float*)d_in[7];
    const float* attn_ln_g = (const float*)d_in[8];
    const float* attn_ln_b = (const float*)d_in[9];
    const float* in_proj_w = (const float*)d_in[10];
    const float* in_proj_b = (const float*)d_in[11];
    const float* out_proj_w= (const float*)d_in[12];
    const float* out_proj_b= (const float*)d_in[13];
    const float* enc1_g    = (const float*)d_in[14];
    const float* enc1_b    = (const float*)d_in[15];
    const float* lin1_w    = (const float*)d_in[16];
    const float* lin1_b    = (const float*)d_in[17];
    const float* lin2_w    = (const float*)d_in[18];
    const float* lin2_b    = (const float*)d_in[19];
    const float* enc2_g    = (const float*)d_in[20];
    const float* enc2_b    = (const float*)d_in[21];
    float* out = (float*)d_out;  // also fp32 scratch (out_pre/h1/h2)

    char* ws = (char*)d_ws;
    size_t off = 0;
    auto alloc = [&](size_t bytes) {
        void* p = ws + off;
        off += (bytes + 255) & ~(size_t)255;
        return p;
    };
    const size_t MT = 8192;
    u16* oe_bf   = (u16*)alloc(MT * 1024 * 2);
    u16* ax_bf   = (u16*)alloc(MT * 1024 * 2);
    char* region = (char*)alloc((size_t)67108864);             // qkv+vt | ff1
    u16* qkv_bf  = (u16*)region;
    u16* vt_bf   = (u16*)(region + (size_t)MT * 3072 * 2);
    u16* ff1_bf  = (u16*)region;
    u16* wb_inproj  = (u16*)alloc((size_t)3072 * 1024 * 2);
    u16* wb_outproj = (u16*)alloc((size_t)1024 * 1024 * 2);
    u16* wb_lin1    = (u16*)alloc((size_t)4096 * 1024 * 2);
    u16* wb_lin2    = (u16*)alloc((size_t)1024 * 4096 * 2);

    hipMemcpyAsync(out, we, MT * 1024 * 4, hipMemcpyDeviceToDevice, stream);
    f2bf_kernel<<<3072, 256, 0, stream>>>(in_proj_w, wb_inproj, 3072 * 1024 / 4);
    f2bf_kernel<<<1024, 256, 0, stream>>>(out_proj_w, wb_outproj, 1024 * 1024 / 4);
    f2bf_kernel<<<4096, 256, 0, stream>>>(lin1_w, wb_lin1, 4096 * 1024 / 4);
    f2bf_kernel<<<4096, 256, 0, stream>>>(lin2_w, wb_lin2, 1024 * 4096 / 4);
    span_kernel<<<16384, 256, 0, stream>>>(we, span_b, span_s, span_t, tag_emb,
                                           gate_w, gate_b, out);
    ln_kernel<false, true, false><<<8192, 256, 0, stream>>>(
        out, attn_ln_g, attn_ln_b, 1e-12f, nullptr, oe_bf, nullptr);
    dim3 g1(32, 24);
    gemm_nt8b<true, false, false><<<g1, 512, 0, stream>>>(
        oe_bf, wb_inproj, in_proj_b, nullptr, qkv_bf, 3072, 1024);
    vtrans_kernel<<<2048, 256, 0, stream>>>(qkv_bf, vt_bf);
    attn_kernel<<<1024, 256, 0, stream>>>(qkv_bf, vt_bf, amask, ax_bf);
    dim3 g2(32, 8);
    gemm_nt8b<false, false, true><<<g2, 512, 0, stream>>>(
        ax_bf, wb_outproj, out_proj_b, oe_bf, out, 1024, 1024);
    ln_kernel<false, true, false><<<8192, 256, 0, stream>>>(
        out, enc1_g, enc1_b, 1e-5f, nullptr, ax_bf, nullptr);
    dim3 g3(32, 32);
    gemm_nt8b<true, true, false><<<g3, 512, 0, stream>>>(
        ax_bf, wb_lin1, lin1_b, nullptr, ff1_bf, 4096, 1024);
    gemm_nt8b<false, false, true><<<g2, 512, 0, stream>>>(
        ff1_bf, wb_lin2, lin2_b, ax_bf, out, 1024, 4096);
    ln_kernel<true, false, true><<<8192, 256, 0, stream>>>(
        out, enc2_g, enc2_b, 1e-5f, out, nullptr, oe_bf);
}